// Round 15
// baseline (1195.489 us; speedup 1.0000x reference)
//
#include <hip/hip_runtime.h>
#include <hip/hip_bf16.h>

// GATv2 x3 layers, MI355X. f32 in/out; edge_index int32.
// R27: k_score asm reverted (R26: tied-constraint v_mov storm, 59.4->77.4us;
// compiler codegen is the confirmed optimum for the f2 loop body). New:
// LANE-PAIR CHANNEL SPLIT in k_score — each (edge,head) handled by lanes
// 2i/2i+1, 32 channels each (8 cb-iters), combined with one shfl_xor(1).
// Halves the per-thread dependent-chain length; doubles waves (16.5k->32.8k).
// Pair lanes share the same ea line (L1-served, HBM flat); W stays
// wave-uniform; head-clustered XCD swizzle preserved (WPH=1641, 8x1026).
// Everything else byte-identical to R25 (best 457.2us): ws-branch agg,
// k_xl, setup, k_eal, k_wet3.

#define NN 10000    // nodes
#define NE 200000   // edges
#define ND 128      // node dim (layer 0 input)
#define ED 16       // edge dim
#define CD 64       // conv dim (per head)
#define NH 5        // heads
#define HC 320      // NH*CD
#define EF 210000   // NE + NN (with self loops)
#define EFP 210048  // EF padded to 128
#define NEG 0.2f
#define WPH 1641    // k_score blocks per head = EFP/128 (128 edges/block)
#define TOT2 8205   // WPH*NH
#define G2 8208     // launched blocks = 8 XCDs * 1026, guard wk>=TOT2
#define NW_AGG 50000   // NH*NN agg waves (head-major)
#define BL_AGG 12504   // 8*1563 blocks of 4 waves, guard g>=NW_AGG
#define PERXA 1563     // agg blocks per XCD

typedef float f2 __attribute__((ext_vector_type(2)));

// ---- CSR build: count ----
__global__ void k_count(const int* __restrict__ dst, int* __restrict__ deg) {
  int e = blockIdx.x * blockDim.x + threadIdx.x;
  if (e >= NE) return;
  atomicAdd(&deg[dst[e]], 1);
}

// ---- CSR build: exclusive scan (single block, 1024 threads x 10 elems) ----
__global__ __launch_bounds__(1024) void k_scan(const int* __restrict__ deg,
                                               int* __restrict__ rowptr) {
  __shared__ int part[1024];
  int t = threadIdx.x;
  int base = t * 10;
  int local[10];
  int s = 0;
  #pragma unroll
  for (int j = 0; j < 10; j++) {
    int i = base + j;
    local[j] = (i < NN) ? deg[i] : 0;
    s += local[j];
  }
  part[t] = s;
  __syncthreads();
  for (int off = 1; off < 1024; off <<= 1) {
    int v = (t >= off) ? part[t - off] : 0;
    __syncthreads();
    part[t] += v;
    __syncthreads();
  }
  int prefix = (t > 0) ? part[t - 1] : 0;
  #pragma unroll
  for (int j = 0; j < 10; j++) {
    int i = base + j;
    if (i < NN) rowptr[i] = prefix;
    prefix += local[j];
  }
  if (t == 1023) rowptr[NN] = prefix;
}

// ---- CSR build: fill ----
__global__ void k_fill(const int* __restrict__ ei, const int* __restrict__ rowptr,
                       int* __restrict__ cursor, int* __restrict__ csr_eid,
                       int* __restrict__ csr_src, int* __restrict__ csr_dst) {
  int e = blockIdx.x * blockDim.x + threadIdx.x;
  if (e >= NE) return;
  int d = ei[NE + e];
  int slot = atomicAdd(&cursor[d], 1);
  int pos = rowptr[d] + slot;
  csr_eid[pos] = e;
  csr_src[pos] = ei[e];
  csr_dst[pos] = d;
}

// ---- ea_csr permute + loop_attr mean, fused (one gather pass) ----
__global__ __launch_bounds__(256) void k_eal(const int* __restrict__ csr_eid,
                                             const float* __restrict__ eattr,
                                             const int* __restrict__ rowptr,
                                             float* __restrict__ ea_csr,
                                             float* __restrict__ loop_attr) {
  int wave = threadIdx.x >> 6, lane = threadIdx.x & 63;
  int d = blockIdx.x * 4 + wave;
  if (d >= NN) return;
  int g = lane >> 4, k = lane & 15;
  int b = rowptr[d], n = rowptr[d + 1] - b;
  float s = 0.f;
  for (int i = g; i < n; i += 4) {
    float v = eattr[(size_t)csr_eid[b + i] * ED + k];
    ea_csr[(size_t)(b + i) * ED + k] = v;
    s += v;
  }
  s += __shfl_xor(s, 16, 64);
  s += __shfl_xor(s, 32, 64);
  if (g == 0) loop_attr[d * ED + k] = s / fmaxf((float)n, 1.0f);
}

// ---- Wpk for ALL 3 layers in one dispatch ----
// Wpk[l][((h*32 + cp)*16 + k)*2 + j] = We_l[k][h*64 + 2*cp + j]
__global__ void k_wet3(const float* __restrict__ We0, const float* __restrict__ We1,
                       const float* __restrict__ We2, float* __restrict__ Wpk) {
  int i = blockIdx.x * blockDim.x + threadIdx.x;
  if (i >= 3 * ED * HC) return;
  int l = i / (ED * HC);
  int r = i - l * (ED * HC);
  const float* We = (l == 0) ? We0 : (l == 1) ? We1 : We2;
  int j  = r & 1;
  int k  = (r >> 1) & 15;
  int cp = (r >> 5) & 31;
  int h  = r >> 10;
  Wpk[i] = We[k * HC + h * CD + cp * 2 + j];
}

// ---- xl = h @ Wl + bl  (node-major xl[node][hc], contiguous 1280B rows) ----
template <int D>
__global__ __launch_bounds__(320) void k_xl(const float* __restrict__ h,
                                            const float* __restrict__ Wl,
                                            const float* __restrict__ bl,
                                            float* __restrict__ xl) {
  constexpr int NPB = 8;
  int node0 = blockIdx.x * NPB;
  int t = threadIdx.x;  // output column 0..319
  float acc[NPB];
  #pragma unroll
  for (int i = 0; i < NPB; i++) acc[i] = 0.f;
  for (int k = 0; k < D; k += 4) {
    float w0 = Wl[(k + 0) * HC + t];
    float w1 = Wl[(k + 1) * HC + t];
    float w2 = Wl[(k + 2) * HC + t];
    float w3 = Wl[(k + 3) * HC + t];
    #pragma unroll
    for (int i = 0; i < NPB; i++) {
      float4 hv = *(const float4*)(h + (size_t)(node0 + i) * D + k);
      acc[i] += hv.x * w0 + hv.y * w1 + hv.z * w2 + hv.w * w3;
    }
  }
  float bv = bl[t];
  #pragma unroll
  for (int i = 0; i < NPB; i++)
    xl[(size_t)(node0 + i) * HC + t] = acc[i] + bv;
}

// ---- scores: LANE PAIR PER (EDGE, HEAD); 32 channels per lane ----
// R25 loop body (compiler-optimal f2 codegen); half = lane&1 selects the
// channel half; one shfl_xor(1) combines; half==0 writes exp(score).
// Head-clustered XCD mapping (contiguous wk slice per XCD -> per-XCD xl
// line working set = one head's 2.56MB; ea lines shared within lane pair).
__global__ __launch_bounds__(256) void k_score(
    const int* __restrict__ csr_src, const int* __restrict__ csr_dst,
    const float* __restrict__ ea_csr, const float* __restrict__ loop_attr,
    const float* __restrict__ xl, const float* __restrict__ Wpk,
    const float* __restrict__ att, float* __restrict__ wP) {
  int bid = blockIdx.x;                       // 0..G2-1
  int wk = (bid & 7) * 1026 + (bid >> 3);     // contiguous slice per XCD
  if (wk >= TOT2) return;
  int h = wk / WPH;                           // head (uniform, magic-div)
  int lb = wk - h * WPH;                      // 128-edge slice within head
  int e = threadIdx.x >> 1, half = threadIdx.x & 1;
  int p = lb * 128 + e;
  if (p >= EF) return;                        // pair-consistent exit
  int s, d;
  const float* ea;
  if (p < NE) { s = csr_src[p]; d = csr_dst[p]; ea = ea_csr + (size_t)p * ED; }
  else        { s = d = p - NE; ea = loop_attr + (size_t)(p - NE) * ED; }
  float eas[16];
  {
    const float4* q = (const float4*)ea;      // pair lanes: same line (L1)
    float4 t0 = q[0], t1 = q[1], t2 = q[2], t3 = q[3];
    eas[0] = t0.x;  eas[1] = t0.y;  eas[2] = t0.z;  eas[3] = t0.w;
    eas[4] = t1.x;  eas[5] = t1.y;  eas[6] = t1.z;  eas[7] = t1.w;
    eas[8] = t2.x;  eas[9] = t2.y;  eas[10] = t2.z; eas[11] = t2.w;
    eas[12] = t3.x; eas[13] = t3.y; eas[14] = t3.z; eas[15] = t3.w;
  }
  const float* xsrow = xl + (size_t)s * HC + h * CD + half * 32;  // 128B half
  const float* xdrow = xl + (size_t)d * HC + h * CD + half * 32;
  const f2* wp = (const f2*)Wpk + ((size_t)h * (CD / 2) + half * 16) * ED;
  const f2* ap = (const f2*)(att + (size_t)h * CD) + half * 16;
  f2 sc2 = {0.f, 0.f};
  const f2 zero = {0.f, 0.f};
  #pragma unroll 4
  for (int cb = 0; cb < 32; cb += 4) {  // 2 channel-pairs per iter, 8 iters
    int cp = cb >> 1;
    float4 xs4 = *(const float4*)(xsrow + cb);
    float4 xd4 = *(const float4*)(xdrow + cb);
    const f2* w0 = wp + (size_t)cp * ED;
    const f2* w1 = w0 + ED;
    f2 z0 = f2{xs4.x, xs4.y} + f2{xd4.x, xd4.y};   // v_pk_add_f32
    f2 z1 = f2{xs4.z, xs4.w} + f2{xd4.z, xd4.w};
    #pragma unroll
    for (int k = 0; k < ED; k++) {                 // 2x v_pk_fma_f32 per k
      z0 += w0[k] * eas[k];
      z1 += w1[k] * eas[k];
    }
    // leaky: max(z,0) + NEG*min(z,0)  (packed, branchless, exact)
    z0 = __builtin_elementwise_max(z0, zero) + NEG * __builtin_elementwise_min(z0, zero);
    z1 = __builtin_elementwise_max(z1, zero) + NEG * __builtin_elementwise_min(z1, zero);
    sc2 += z0 * ap[cp];
    sc2 += z1 * ap[cp + 1];
  }
  float sc = sc2.x + sc2.y;
  sc += __shfl_xor(sc, 1, 64);                // combine channel halves
  if (half == 0) {
    sc = fminf(fmaxf(sc, -60.f), 60.f);       // clamp never binds
    wP[(size_t)h * EFP + p] = __expf(sc);     // 32 lanes, stride-1 -> 128B
  }
}

// ---- aggregation A (fallback, R23): block per node, wave per head ----
__global__ __launch_bounds__(320) void k_agg(
    const int* __restrict__ csr_src, const int* __restrict__ rowptr,
    const float* __restrict__ wP, const float* __restrict__ xl,
    const float* __restrict__ bias, float* __restrict__ out) {
  __shared__ float s_v[NH][CD];
  int h = threadIdx.x >> 6, lane = threadIdx.x & 63;
  int d = blockIdx.x;
  int b = rowptr[d], pe = rowptr[d + 1];
  const float* sp = wP + (size_t)h * EFP;
  const float* xlh = xl + h * CD + lane;               // node-major layout
  float dn = sp[NE + d];
  float acc = dn * xlh[(size_t)d * HC];
  int p = b;
  for (; p + 8 <= pe; p += 8) {
    int s0 = csr_src[p + 0], s1 = csr_src[p + 1];
    int s2 = csr_src[p + 2], s3 = csr_src[p + 3];
    int s4 = csr_src[p + 4], s5 = csr_src[p + 5];
    int s6 = csr_src[p + 6], s7 = csr_src[p + 7];
    float w0 = sp[p + 0], w1 = sp[p + 1], w2 = sp[p + 2], w3 = sp[p + 3];
    float w4 = sp[p + 4], w5 = sp[p + 5], w6 = sp[p + 6], w7 = sp[p + 7];
    float x0 = xlh[(size_t)s0 * HC];
    float x1 = xlh[(size_t)s1 * HC];
    float x2 = xlh[(size_t)s2 * HC];
    float x3 = xlh[(size_t)s3 * HC];
    float x4 = xlh[(size_t)s4 * HC];
    float x5 = xlh[(size_t)s5 * HC];
    float x6 = xlh[(size_t)s6 * HC];
    float x7 = xlh[(size_t)s7 * HC];
    dn += ((w0 + w1) + (w2 + w3)) + ((w4 + w5) + (w6 + w7));
    acc += ((w0 * x0 + w1 * x1) + (w2 * x2 + w3 * x3)) +
           ((w4 * x4 + w5 * x5) + (w6 * x6 + w7 * x7));
  }
  for (; p + 4 <= pe; p += 4) {
    int s0 = csr_src[p + 0], s1 = csr_src[p + 1];
    int s2 = csr_src[p + 2], s3 = csr_src[p + 3];
    float w0 = sp[p + 0], w1 = sp[p + 1], w2 = sp[p + 2], w3 = sp[p + 3];
    float x0 = xlh[(size_t)s0 * HC];
    float x1 = xlh[(size_t)s1 * HC];
    float x2 = xlh[(size_t)s2 * HC];
    float x3 = xlh[(size_t)s3 * HC];
    dn += (w0 + w1) + (w2 + w3);
    acc += (w0 * x0 + w1 * x1) + (w2 * x2 + w3 * x3);
  }
  for (; p < pe; p++) {
    int s0 = csr_src[p];
    float w0 = sp[p];
    dn += w0;
    acc += w0 * xlh[(size_t)s0 * HC];
  }
  s_v[h][lane] = acc / dn;
  __syncthreads();
  if (h == 0) {
    float v = s_v[0][lane] + s_v[1][lane] + s_v[2][lane] + s_v[3][lane] + s_v[4][lane];
    v = v * (1.0f / NH) + bias[lane];
    v = v > 0.f ? v : expm1f(v);
    out[(size_t)d * CD + lane] = v;
  }
}

// ---- aggregation B: ONE WAVE PER (HEAD,NODE), head-clustered, NON-ATOMIC --
__global__ __launch_bounds__(256) void k_agg2p(
    const int* __restrict__ csr_src, const int* __restrict__ rowptr,
    const float* __restrict__ wP, const float* __restrict__ xl,
    float* __restrict__ partial) {
  int bid = blockIdx.x;
  int b2 = (bid & 7) * PERXA + (bid >> 3);   // contiguous per XCD
  int wv = threadIdx.x >> 6, lane = threadIdx.x & 63;
  int g = b2 * 4 + wv;                        // head-major wave id
  if (g >= NW_AGG) return;
  int h = g / NN;                             // uniform (magic-div)
  int d = g - h * NN;
  int b = rowptr[d], pe = rowptr[d + 1];
  const float* sp = wP + (size_t)h * EFP;
  const float* xlh = xl + h * CD + lane;      // node-major, head slice
  float dn = sp[NE + d];
  float acc = dn * xlh[(size_t)d * HC];
  int p = b;
  for (; p + 8 <= pe; p += 8) {
    int s0 = csr_src[p + 0], s1 = csr_src[p + 1];
    int s2 = csr_src[p + 2], s3 = csr_src[p + 3];
    int s4 = csr_src[p + 4], s5 = csr_src[p + 5];
    int s6 = csr_src[p + 6], s7 = csr_src[p + 7];
    float w0 = sp[p + 0], w1 = sp[p + 1], w2 = sp[p + 2], w3 = sp[p + 3];
    float w4 = sp[p + 4], w5 = sp[p + 5], w6 = sp[p + 6], w7 = sp[p + 7];
    float x0 = xlh[(size_t)s0 * HC];
    float x1 = xlh[(size_t)s1 * HC];
    float x2 = xlh[(size_t)s2 * HC];
    float x3 = xlh[(size_t)s3 * HC];
    float x4 = xlh[(size_t)s4 * HC];
    float x5 = xlh[(size_t)s5 * HC];
    float x6 = xlh[(size_t)s6 * HC];
    float x7 = xlh[(size_t)s7 * HC];
    dn += ((w0 + w1) + (w2 + w3)) + ((w4 + w5) + (w6 + w7));
    acc += ((w0 * x0 + w1 * x1) + (w2 * x2 + w3 * x3)) +
           ((w4 * x4 + w5 * x5) + (w6 * x6 + w7 * x7));
  }
  for (; p + 4 <= pe; p += 4) {
    int s0 = csr_src[p + 0], s1 = csr_src[p + 1];
    int s2 = csr_src[p + 2], s3 = csr_src[p + 3];
    float w0 = sp[p + 0], w1 = sp[p + 1], w2 = sp[p + 2], w3 = sp[p + 3];
    float x0 = xlh[(size_t)s0 * HC];
    float x1 = xlh[(size_t)s1 * HC];
    float x2 = xlh[(size_t)s2 * HC];
    float x3 = xlh[(size_t)s3 * HC];
    dn += (w0 + w1) + (w2 + w3);
    acc += (w0 * x0 + w1 * x1) + (w2 * x2 + w3 * x3);
  }
  for (; p < pe; p++) {
    int s0 = csr_src[p];
    float w0 = sp[p];
    dn += w0;
    acc += w0 * xlh[(size_t)s0 * HC];
  }
  partial[(size_t)g * CD + lane] = acc / dn;  // coalesced 256B per wave
}

// ---- combine from partials: out = elu(mean_h partial + bias) ----
__global__ __launch_bounds__(256) void k_combp(const float* __restrict__ partial,
                                               const float* __restrict__ bias,
                                               float* __restrict__ out) {
  int idx = blockIdx.x * blockDim.x + threadIdx.x;  // d*CD + c
  if (idx >= NN * CD) return;
  int c = idx & (CD - 1);
  float v = partial[idx];
  #pragma unroll
  for (int h = 1; h < NH; h++)
    v += partial[(size_t)h * NN * CD + idx];
  v = v * (1.0f / NH) + bias[c];
  v = v > 0.f ? v : expm1f(v);
  out[idx] = v;
}

static inline size_t aln(size_t x) { return (x + 255) & ~(size_t)255; }

extern "C" void kernel_launch(void* const* d_in, const int* in_sizes, int n_in,
                              void* d_out, int out_size, void* d_ws, size_t ws_size,
                              hipStream_t stream) {
  const float* x = (const float*)d_in[0];
  const int* ei = (const int*)d_in[1];      // [2, NE]: src row then dst row
  const float* eattr = (const float*)d_in[2];

  char* w = (char*)d_ws;
  int* degi      = (int*)w;                 w += aln(NN * 4);
  int* cursor    = (int*)w;                 w += aln(NN * 4);
  int* rowptr    = (int*)w;                 w += aln((NN + 1) * 4);
  int* csr_eid   = (int*)w;                 w += aln((size_t)NE * 4);
  int* csr_src   = (int*)w;                 w += aln((size_t)NE * 4);
  int* csr_dst   = (int*)w;                 w += aln((size_t)NE * 4);
  float* loop_attr = (float*)w;             w += aln((size_t)NN * ED * 4);
  float* ea_csr  = (float*)w;               w += aln((size_t)NE * ED * 4);
  float* xl      = (float*)w;               w += aln((size_t)NN * HC * 4);
  float* wPbuf   = (float*)w;               w += aln((size_t)NH * EFP * 4);
  float* Wpk     = (float*)w;               w += aln((size_t)3 * ED * HC * 4);
  float* hbuf    = (float*)w;               w += aln((size_t)NN * CD * 4);
  float* partial = (float*)w;               w += aln((size_t)NH * NN * CD * 4);
  size_t needed = (size_t)(w - (char*)d_ws);
  bool big_ws = (ws_size >= needed);        // runtime probe; safe either way

  // graph structure + permuted edge attrs + all-layer Wpk (layer-invariant)
  hipMemsetAsync(degi, 0, 2 * aln(NN * 4), stream);   // degi + cursor (adjacent)
  k_count<<<(NE + 255) / 256, 256, 0, stream>>>(ei + NE, degi);
  k_scan<<<1, 1024, 0, stream>>>(degi, rowptr);
  k_fill<<<(NE + 255) / 256, 256, 0, stream>>>(ei, rowptr, cursor, csr_eid, csr_src, csr_dst);
  k_eal<<<(NN + 3) / 4, 256, 0, stream>>>(csr_eid, eattr, rowptr, ea_csr, loop_attr);
  k_wet3<<<(3 * ED * HC + 255) / 256, 256, 0, stream>>>(
      (const float*)d_in[5], (const float*)d_in[10], (const float*)d_in[15], Wpk);

  for (int l = 0; l < 3; l++) {
    const float* Wl  = (const float*)d_in[3 + 5 * l];
    const float* bl  = (const float*)d_in[4 + 5 * l];
    const float* att = (const float*)d_in[6 + 5 * l];
    const float* b   = (const float*)d_in[7 + 5 * l];

    if (l == 0) k_xl<ND><<<NN / 8, 320, 0, stream>>>(x, Wl, bl, xl);
    else        k_xl<CD><<<NN / 8, 320, 0, stream>>>(hbuf, Wl, bl, xl);

    k_score<<<G2, 256, 0, stream>>>(csr_src, csr_dst, ea_csr, loop_attr,
                                    xl, Wpk + (size_t)l * ED * HC, att, wPbuf);

    float* dst_out = (l < 2) ? hbuf : (float*)d_out;
    if (big_ws) {
      k_agg2p<<<BL_AGG, 256, 0, stream>>>(csr_src, rowptr, wPbuf, xl, partial);
      k_combp<<<(NN * CD + 255) / 256, 256, 0, stream>>>(partial, b, dst_out);
    } else {
      k_agg<<<NN, 320, 0, stream>>>(csr_src, rowptr, wPbuf, xl, b, dst_out);
    }
  }
}

// Round 16
// 497.366 us; speedup vs baseline: 2.4036x; 2.4036x over previous
//
#include <hip/hip_runtime.h>
#include <hip/hip_bf16.h>

// GATv2 x3 layers, MI355X. f32 in/out; edge_index int32.
// R28: k_score processes TWO edges per thread (p and p+105024, same head).
// R27's lesson (305us, SGPR 112->32): 'half' in W addresses demoted scalar
// s_loads to divergent vector loads. This change keeps the three invariants
// of the fast body: per-thread gather streams (now 4 rows + 2 ea in flight),
// wave-uniform W (h block-uniform -> s_load), compiler-scheduled f2 math.
// Same mechanism as R23's k_agg 8-wide win. VGPR ~40->~76 (8->6 waves/SIMD,
// the trade R23 made and won). Unroll 2. Pad tail skips store.
// Everything else byte-identical to R25 (best 457.2us).

#define NN 10000    // nodes
#define NE 200000   // edges
#define ND 128      // node dim (layer 0 input)
#define ED 16       // edge dim
#define CD 64       // conv dim (per head)
#define NH 5        // heads
#define HC 320      // NH*CD
#define EF 210000   // NE + NN (with self loops)
#define EFP 210048  // EF padded to 128
#define NEG 0.2f
#define HALF 105024    // EFP/2; thread covers p and p+HALF
#define HPB 411        // blocks per head = ceil(HALF/256)
#define TOT3 2055      // HPB*NH
#define G3 2056        // launched blocks = 8 XCDs * 257, guard wk>=TOT3
#define NW_AGG 50000   // NH*NN agg waves (head-major)
#define BL_AGG 12504   // 8*1563 blocks of 4 waves, guard g>=NW_AGG
#define PERXA 1563     // agg blocks per XCD

typedef float f2 __attribute__((ext_vector_type(2)));

// ---- CSR build: count ----
__global__ void k_count(const int* __restrict__ dst, int* __restrict__ deg) {
  int e = blockIdx.x * blockDim.x + threadIdx.x;
  if (e >= NE) return;
  atomicAdd(&deg[dst[e]], 1);
}

// ---- CSR build: exclusive scan (single block, 1024 threads x 10 elems) ----
__global__ __launch_bounds__(1024) void k_scan(const int* __restrict__ deg,
                                               int* __restrict__ rowptr) {
  __shared__ int part[1024];
  int t = threadIdx.x;
  int base = t * 10;
  int local[10];
  int s = 0;
  #pragma unroll
  for (int j = 0; j < 10; j++) {
    int i = base + j;
    local[j] = (i < NN) ? deg[i] : 0;
    s += local[j];
  }
  part[t] = s;
  __syncthreads();
  for (int off = 1; off < 1024; off <<= 1) {
    int v = (t >= off) ? part[t - off] : 0;
    __syncthreads();
    part[t] += v;
    __syncthreads();
  }
  int prefix = (t > 0) ? part[t - 1] : 0;
  #pragma unroll
  for (int j = 0; j < 10; j++) {
    int i = base + j;
    if (i < NN) rowptr[i] = prefix;
    prefix += local[j];
  }
  if (t == 1023) rowptr[NN] = prefix;
}

// ---- CSR build: fill ----
__global__ void k_fill(const int* __restrict__ ei, const int* __restrict__ rowptr,
                       int* __restrict__ cursor, int* __restrict__ csr_eid,
                       int* __restrict__ csr_src, int* __restrict__ csr_dst) {
  int e = blockIdx.x * blockDim.x + threadIdx.x;
  if (e >= NE) return;
  int d = ei[NE + e];
  int slot = atomicAdd(&cursor[d], 1);
  int pos = rowptr[d] + slot;
  csr_eid[pos] = e;
  csr_src[pos] = ei[e];
  csr_dst[pos] = d;
}

// ---- ea_csr permute + loop_attr mean, fused (one gather pass) ----
__global__ __launch_bounds__(256) void k_eal(const int* __restrict__ csr_eid,
                                             const float* __restrict__ eattr,
                                             const int* __restrict__ rowptr,
                                             float* __restrict__ ea_csr,
                                             float* __restrict__ loop_attr) {
  int wave = threadIdx.x >> 6, lane = threadIdx.x & 63;
  int d = blockIdx.x * 4 + wave;
  if (d >= NN) return;
  int g = lane >> 4, k = lane & 15;
  int b = rowptr[d], n = rowptr[d + 1] - b;
  float s = 0.f;
  for (int i = g; i < n; i += 4) {
    float v = eattr[(size_t)csr_eid[b + i] * ED + k];
    ea_csr[(size_t)(b + i) * ED + k] = v;
    s += v;
  }
  s += __shfl_xor(s, 16, 64);
  s += __shfl_xor(s, 32, 64);
  if (g == 0) loop_attr[d * ED + k] = s / fmaxf((float)n, 1.0f);
}

// ---- Wpk for ALL 3 layers in one dispatch ----
// Wpk[l][((h*32 + cp)*16 + k)*2 + j] = We_l[k][h*64 + 2*cp + j]
__global__ void k_wet3(const float* __restrict__ We0, const float* __restrict__ We1,
                       const float* __restrict__ We2, float* __restrict__ Wpk) {
  int i = blockIdx.x * blockDim.x + threadIdx.x;
  if (i >= 3 * ED * HC) return;
  int l = i / (ED * HC);
  int r = i - l * (ED * HC);
  const float* We = (l == 0) ? We0 : (l == 1) ? We1 : We2;
  int j  = r & 1;
  int k  = (r >> 1) & 15;
  int cp = (r >> 5) & 31;
  int h  = r >> 10;
  Wpk[i] = We[k * HC + h * CD + cp * 2 + j];
}

// ---- xl = h @ Wl + bl  (node-major xl[node][hc], contiguous 1280B rows) ----
template <int D>
__global__ __launch_bounds__(320) void k_xl(const float* __restrict__ h,
                                            const float* __restrict__ Wl,
                                            const float* __restrict__ bl,
                                            float* __restrict__ xl) {
  constexpr int NPB = 8;
  int node0 = blockIdx.x * NPB;
  int t = threadIdx.x;  // output column 0..319
  float acc[NPB];
  #pragma unroll
  for (int i = 0; i < NPB; i++) acc[i] = 0.f;
  for (int k = 0; k < D; k += 4) {
    float w0 = Wl[(k + 0) * HC + t];
    float w1 = Wl[(k + 1) * HC + t];
    float w2 = Wl[(k + 2) * HC + t];
    float w3 = Wl[(k + 3) * HC + t];
    #pragma unroll
    for (int i = 0; i < NPB; i++) {
      float4 hv = *(const float4*)(h + (size_t)(node0 + i) * D + k);
      acc[i] += hv.x * w0 + hv.y * w1 + hv.z * w2 + hv.w * w3;
    }
  }
  float bv = bl[t];
  #pragma unroll
  for (int i = 0; i < NPB; i++)
    xl[(size_t)(node0 + i) * HC + t] = acc[i] + bv;
}

// ---- scores: ONE THREAD PER TWO (EDGE, HEAD) ITEMS (p and p+HALF) ----
// R25 loop body x2 edges, shared wave-uniform W/att (scalar pipe). 4 row
// gathers + 2 ea streams in flight per thread. Head-clustered XCD mapping.
__global__ __launch_bounds__(256) void k_score(
    const int* __restrict__ csr_src, const int* __restrict__ csr_dst,
    const float* __restrict__ ea_csr, const float* __restrict__ loop_attr,
    const float* __restrict__ xl, const float* __restrict__ Wpk,
    const float* __restrict__ att, float* __restrict__ wP) {
  int bid = blockIdx.x;                       // 0..G3-1
  int wk = (bid & 7) * 257 + (bid >> 3);      // contiguous slice per XCD
  if (wk >= TOT3) return;
  int h = wk / HPB;                           // head (uniform, magic-div)
  int lb = wk - h * HPB;
  int p = lb * 256 + threadIdx.x;             // edge A: always real (p < NE)
  if (p >= HALF) return;
  int p2 = p + HALF;                          // edge B: real | self | pad
  // edge A context
  int sA = csr_src[p], dA = csr_dst[p];
  const float* eaA = ea_csr + (size_t)p * ED;
  // edge B context
  int sB, dB;
  const float* eaB;
  bool storeB = (p2 < EF);
  if (p2 < NE)      { sB = csr_src[p2]; dB = csr_dst[p2]; eaB = ea_csr + (size_t)p2 * ED; }
  else if (p2 < EF) { sB = dB = p2 - NE; eaB = loop_attr + (size_t)(p2 - NE) * ED; }
  else              { sB = dB = 0; eaB = loop_attr; }
  float easA[16], easB[16];
  {
    const float4* qa = (const float4*)eaA;
    float4 t0 = qa[0], t1 = qa[1], t2 = qa[2], t3 = qa[3];
    easA[0] = t0.x;  easA[1] = t0.y;  easA[2] = t0.z;  easA[3] = t0.w;
    easA[4] = t1.x;  easA[5] = t1.y;  easA[6] = t1.z;  easA[7] = t1.w;
    easA[8] = t2.x;  easA[9] = t2.y;  easA[10] = t2.z; easA[11] = t2.w;
    easA[12] = t3.x; easA[13] = t3.y; easA[14] = t3.z; easA[15] = t3.w;
    const float4* qb = (const float4*)eaB;
    float4 u0 = qb[0], u1 = qb[1], u2 = qb[2], u3 = qb[3];
    easB[0] = u0.x;  easB[1] = u0.y;  easB[2] = u0.z;  easB[3] = u0.w;
    easB[4] = u1.x;  easB[5] = u1.y;  easB[6] = u1.z;  easB[7] = u1.w;
    easB[8] = u2.x;  easB[9] = u2.y;  easB[10] = u2.z; easB[11] = u2.w;
    easB[12] = u3.x; easB[13] = u3.y; easB[14] = u3.z; easB[15] = u3.w;
  }
  const float* xsA = xl + (size_t)sA * HC + h * CD;   // node-major rows
  const float* xdA = xl + (size_t)dA * HC + h * CD;
  const float* xsB = xl + (size_t)sB * HC + h * CD;
  const float* xdB = xl + (size_t)dB * HC + h * CD;
  const f2* wp = (const f2*)Wpk + (size_t)h * (CD / 2) * ED;  // wave-uniform
  const f2* ap = (const f2*)(att + (size_t)h * CD);
  f2 scA = {0.f, 0.f}, scB = {0.f, 0.f};
  const f2 zero = {0.f, 0.f};
  #pragma unroll 2
  for (int cb = 0; cb < CD; cb += 4) {  // 16 iters, 2 chan-pairs x 2 edges
    int cp = cb >> 1;
    float4 xsa = *(const float4*)(xsA + cb);
    float4 xda = *(const float4*)(xdA + cb);
    float4 xsb = *(const float4*)(xsB + cb);
    float4 xdb = *(const float4*)(xdB + cb);
    const f2* w0 = wp + (size_t)cp * ED;
    const f2* w1 = w0 + ED;
    f2 z0a = f2{xsa.x, xsa.y} + f2{xda.x, xda.y};
    f2 z1a = f2{xsa.z, xsa.w} + f2{xda.z, xda.w};
    f2 z0b = f2{xsb.x, xsb.y} + f2{xdb.x, xdb.y};
    f2 z1b = f2{xsb.z, xsb.w} + f2{xdb.z, xdb.w};
    #pragma unroll
    for (int k = 0; k < ED; k++) {
      f2 wv0 = w0[k], wv1 = w1[k];             // scalar loads, shared
      z0a += wv0 * easA[k];
      z1a += wv1 * easA[k];
      z0b += wv0 * easB[k];
      z1b += wv1 * easB[k];
    }
    z0a = __builtin_elementwise_max(z0a, zero) + NEG * __builtin_elementwise_min(z0a, zero);
    z1a = __builtin_elementwise_max(z1a, zero) + NEG * __builtin_elementwise_min(z1a, zero);
    z0b = __builtin_elementwise_max(z0b, zero) + NEG * __builtin_elementwise_min(z0b, zero);
    z1b = __builtin_elementwise_max(z1b, zero) + NEG * __builtin_elementwise_min(z1b, zero);
    f2 a0 = ap[cp], a1 = ap[cp + 1];
    scA += z0a * a0;
    scA += z1a * a1;
    scB += z0b * a0;
    scB += z1b * a1;
  }
  float sa = scA.x + scA.y;
  sa = fminf(fmaxf(sa, -60.f), 60.f);
  wP[(size_t)h * EFP + p] = __expf(sa);
  float sb = scB.x + scB.y;
  sb = fminf(fmaxf(sb, -60.f), 60.f);
  if (storeB) wP[(size_t)h * EFP + p2] = __expf(sb);
}

// ---- aggregation A (fallback, R23): block per node, wave per head ----
__global__ __launch_bounds__(320) void k_agg(
    const int* __restrict__ csr_src, const int* __restrict__ rowptr,
    const float* __restrict__ wP, const float* __restrict__ xl,
    const float* __restrict__ bias, float* __restrict__ out) {
  __shared__ float s_v[NH][CD];
  int h = threadIdx.x >> 6, lane = threadIdx.x & 63;
  int d = blockIdx.x;
  int b = rowptr[d], pe = rowptr[d + 1];
  const float* sp = wP + (size_t)h * EFP;
  const float* xlh = xl + h * CD + lane;               // node-major layout
  float dn = sp[NE + d];
  float acc = dn * xlh[(size_t)d * HC];
  int p = b;
  for (; p + 8 <= pe; p += 8) {
    int s0 = csr_src[p + 0], s1 = csr_src[p + 1];
    int s2 = csr_src[p + 2], s3 = csr_src[p + 3];
    int s4 = csr_src[p + 4], s5 = csr_src[p + 5];
    int s6 = csr_src[p + 6], s7 = csr_src[p + 7];
    float w0 = sp[p + 0], w1 = sp[p + 1], w2 = sp[p + 2], w3 = sp[p + 3];
    float w4 = sp[p + 4], w5 = sp[p + 5], w6 = sp[p + 6], w7 = sp[p + 7];
    float x0 = xlh[(size_t)s0 * HC];
    float x1 = xlh[(size_t)s1 * HC];
    float x2 = xlh[(size_t)s2 * HC];
    float x3 = xlh[(size_t)s3 * HC];
    float x4 = xlh[(size_t)s4 * HC];
    float x5 = xlh[(size_t)s5 * HC];
    float x6 = xlh[(size_t)s6 * HC];
    float x7 = xlh[(size_t)s7 * HC];
    dn += ((w0 + w1) + (w2 + w3)) + ((w4 + w5) + (w6 + w7));
    acc += ((w0 * x0 + w1 * x1) + (w2 * x2 + w3 * x3)) +
           ((w4 * x4 + w5 * x5) + (w6 * x6 + w7 * x7));
  }
  for (; p + 4 <= pe; p += 4) {
    int s0 = csr_src[p + 0], s1 = csr_src[p + 1];
    int s2 = csr_src[p + 2], s3 = csr_src[p + 3];
    float w0 = sp[p + 0], w1 = sp[p + 1], w2 = sp[p + 2], w3 = sp[p + 3];
    float x0 = xlh[(size_t)s0 * HC];
    float x1 = xlh[(size_t)s1 * HC];
    float x2 = xlh[(size_t)s2 * HC];
    float x3 = xlh[(size_t)s3 * HC];
    dn += (w0 + w1) + (w2 + w3);
    acc += (w0 * x0 + w1 * x1) + (w2 * x2 + w3 * x3);
  }
  for (; p < pe; p++) {
    int s0 = csr_src[p];
    float w0 = sp[p];
    dn += w0;
    acc += w0 * xlh[(size_t)s0 * HC];
  }
  s_v[h][lane] = acc / dn;
  __syncthreads();
  if (h == 0) {
    float v = s_v[0][lane] + s_v[1][lane] + s_v[2][lane] + s_v[3][lane] + s_v[4][lane];
    v = v * (1.0f / NH) + bias[lane];
    v = v > 0.f ? v : expm1f(v);
    out[(size_t)d * CD + lane] = v;
  }
}

// ---- aggregation B: ONE WAVE PER (HEAD,NODE), head-clustered, NON-ATOMIC --
__global__ __launch_bounds__(256) void k_agg2p(
    const int* __restrict__ csr_src, const int* __restrict__ rowptr,
    const float* __restrict__ wP, const float* __restrict__ xl,
    float* __restrict__ partial) {
  int bid = blockIdx.x;
  int b2 = (bid & 7) * PERXA + (bid >> 3);   // contiguous per XCD
  int wv = threadIdx.x >> 6, lane = threadIdx.x & 63;
  int g = b2 * 4 + wv;                        // head-major wave id
  if (g >= NW_AGG) return;
  int h = g / NN;                             // uniform (magic-div)
  int d = g - h * NN;
  int b = rowptr[d], pe = rowptr[d + 1];
  const float* sp = wP + (size_t)h * EFP;
  const float* xlh = xl + h * CD + lane;      // node-major, head slice
  float dn = sp[NE + d];
  float acc = dn * xlh[(size_t)d * HC];
  int p = b;
  for (; p + 8 <= pe; p += 8) {
    int s0 = csr_src[p + 0], s1 = csr_src[p + 1];
    int s2 = csr_src[p + 2], s3 = csr_src[p + 3];
    int s4 = csr_src[p + 4], s5 = csr_src[p + 5];
    int s6 = csr_src[p + 6], s7 = csr_src[p + 7];
    float w0 = sp[p + 0], w1 = sp[p + 1], w2 = sp[p + 2], w3 = sp[p + 3];
    float w4 = sp[p + 4], w5 = sp[p + 5], w6 = sp[p + 6], w7 = sp[p + 7];
    float x0 = xlh[(size_t)s0 * HC];
    float x1 = xlh[(size_t)s1 * HC];
    float x2 = xlh[(size_t)s2 * HC];
    float x3 = xlh[(size_t)s3 * HC];
    float x4 = xlh[(size_t)s4 * HC];
    float x5 = xlh[(size_t)s5 * HC];
    float x6 = xlh[(size_t)s6 * HC];
    float x7 = xlh[(size_t)s7 * HC];
    dn += ((w0 + w1) + (w2 + w3)) + ((w4 + w5) + (w6 + w7));
    acc += ((w0 * x0 + w1 * x1) + (w2 * x2 + w3 * x3)) +
           ((w4 * x4 + w5 * x5) + (w6 * x6 + w7 * x7));
  }
  for (; p + 4 <= pe; p += 4) {
    int s0 = csr_src[p + 0], s1 = csr_src[p + 1];
    int s2 = csr_src[p + 2], s3 = csr_src[p + 3];
    float w0 = sp[p + 0], w1 = sp[p + 1], w2 = sp[p + 2], w3 = sp[p + 3];
    float x0 = xlh[(size_t)s0 * HC];
    float x1 = xlh[(size_t)s1 * HC];
    float x2 = xlh[(size_t)s2 * HC];
    float x3 = xlh[(size_t)s3 * HC];
    dn += (w0 + w1) + (w2 + w3);
    acc += (w0 * x0 + w1 * x1) + (w2 * x2 + w3 * x3);
  }
  for (; p < pe; p++) {
    int s0 = csr_src[p];
    float w0 = sp[p];
    dn += w0;
    acc += w0 * xlh[(size_t)s0 * HC];
  }
  partial[(size_t)g * CD + lane] = acc / dn;  // coalesced 256B per wave
}

// ---- combine from partials: out = elu(mean_h partial + bias) ----
__global__ __launch_bounds__(256) void k_combp(const float* __restrict__ partial,
                                               const float* __restrict__ bias,
                                               float* __restrict__ out) {
  int idx = blockIdx.x * blockDim.x + threadIdx.x;  // d*CD + c
  if (idx >= NN * CD) return;
  int c = idx & (CD - 1);
  float v = partial[idx];
  #pragma unroll
  for (int h = 1; h < NH; h++)
    v += partial[(size_t)h * NN * CD + idx];
  v = v * (1.0f / NH) + bias[c];
  v = v > 0.f ? v : expm1f(v);
  out[idx] = v;
}

static inline size_t aln(size_t x) { return (x + 255) & ~(size_t)255; }

extern "C" void kernel_launch(void* const* d_in, const int* in_sizes, int n_in,
                              void* d_out, int out_size, void* d_ws, size_t ws_size,
                              hipStream_t stream) {
  const float* x = (const float*)d_in[0];
  const int* ei = (const int*)d_in[1];      // [2, NE]: src row then dst row
  const float* eattr = (const float*)d_in[2];

  char* w = (char*)d_ws;
  int* degi      = (int*)w;                 w += aln(NN * 4);
  int* cursor    = (int*)w;                 w += aln(NN * 4);
  int* rowptr    = (int*)w;                 w += aln((NN + 1) * 4);
  int* csr_eid   = (int*)w;                 w += aln((size_t)NE * 4);
  int* csr_src   = (int*)w;                 w += aln((size_t)NE * 4);
  int* csr_dst   = (int*)w;                 w += aln((size_t)NE * 4);
  float* loop_attr = (float*)w;             w += aln((size_t)NN * ED * 4);
  float* ea_csr  = (float*)w;               w += aln((size_t)NE * ED * 4);
  float* xl      = (float*)w;               w += aln((size_t)NN * HC * 4);
  float* wPbuf   = (float*)w;               w += aln((size_t)NH * EFP * 4);
  float* Wpk     = (float*)w;               w += aln((size_t)3 * ED * HC * 4);
  float* hbuf    = (float*)w;               w += aln((size_t)NN * CD * 4);
  float* partial = (float*)w;               w += aln((size_t)NH * NN * CD * 4);
  size_t needed = (size_t)(w - (char*)d_ws);
  bool big_ws = (ws_size >= needed);        // runtime probe; safe either way

  // graph structure + permuted edge attrs + all-layer Wpk (layer-invariant)
  hipMemsetAsync(degi, 0, 2 * aln(NN * 4), stream);   // degi + cursor (adjacent)
  k_count<<<(NE + 255) / 256, 256, 0, stream>>>(ei + NE, degi);
  k_scan<<<1, 1024, 0, stream>>>(degi, rowptr);
  k_fill<<<(NE + 255) / 256, 256, 0, stream>>>(ei, rowptr, cursor, csr_eid, csr_src, csr_dst);
  k_eal<<<(NN + 3) / 4, 256, 0, stream>>>(csr_eid, eattr, rowptr, ea_csr, loop_attr);
  k_wet3<<<(3 * ED * HC + 255) / 256, 256, 0, stream>>>(
      (const float*)d_in[5], (const float*)d_in[10], (const float*)d_in[15], Wpk);

  for (int l = 0; l < 3; l++) {
    const float* Wl  = (const float*)d_in[3 + 5 * l];
    const float* bl  = (const float*)d_in[4 + 5 * l];
    const float* att = (const float*)d_in[6 + 5 * l];
    const float* b   = (const float*)d_in[7 + 5 * l];

    if (l == 0) k_xl<ND><<<NN / 8, 320, 0, stream>>>(x, Wl, bl, xl);
    else        k_xl<CD><<<NN / 8, 320, 0, stream>>>(hbuf, Wl, bl, xl);

    k_score<<<G3, 256, 0, stream>>>(csr_src, csr_dst, ea_csr, loop_attr,
                                    xl, Wpk + (size_t)l * ED * HC, att, wPbuf);

    float* dst_out = (l < 2) ? hbuf : (float*)d_out;
    if (big_ws) {
      k_agg2p<<<BL_AGG, 256, 0, stream>>>(csr_src, rowptr, wPbuf, xl, partial);
      k_combp<<<(NN * CD + 255) / 256, 256, 0, stream>>>(partial, b, dst_out);
    } else {
      k_agg<<<NN, 320, 0, stream>>>(csr_src, rowptr, wPbuf, xl, b, dst_out);
    }
  }
}

// Round 17
// 459.428 us; speedup vs baseline: 2.6021x; 1.0826x over previous
//
#include <hip/hip_runtime.h>
#include <hip/hip_bf16.h>

// GATv2 x3 layers, MI355X. f32 in/out; edge_index int32.
// R29 = R25 byte-identical revert (measured best: 457.2us).
// Session record on k_score: five alternatives to this body regressed —
// wave-cooperative (R15/R16), inline-asm pk_fma (R26), lane-pair split
// (R27: scalar->vector W-load demotion), 2-edge ILP (R28: TLP loss).
// Fast-body invariants: per-thread gather streams, wave-uniform scalar W
// loads, compiler-scheduled f2 math, max wave count, head-clustered XCD
// mapping (L2-resident 2.56MB head slice). agg probed 3 ways; non-score
// time invariant ~283us (agg ~37us/layer + dispatch-chain overhead).

#define NN 10000    // nodes
#define NE 200000   // edges
#define ND 128      // node dim (layer 0 input)
#define ED 16       // edge dim
#define CD 64       // conv dim (per head)
#define NH 5        // heads
#define HC 320      // NH*CD
#define EF 210000   // NE + NN (with self loops)
#define EFP 210048  // EF padded to 64
#define NEG 0.2f
#define PB 824      // k_score p-blocks per head (824*256 >= EF)
#define TOTB 4120   // PB*NH total k_score blocks = 8 XCDs * 515
#define PERX 515    // k_score work items per XCD
#define NW_AGG 50000   // NH*NN agg waves (head-major)
#define BL_AGG 12504   // 8*1563 blocks of 4 waves, guard g>=NW_AGG
#define PERXA 1563     // agg blocks per XCD

typedef float f2 __attribute__((ext_vector_type(2)));

// ---- CSR build: count ----
__global__ void k_count(const int* __restrict__ dst, int* __restrict__ deg) {
  int e = blockIdx.x * blockDim.x + threadIdx.x;
  if (e >= NE) return;
  atomicAdd(&deg[dst[e]], 1);
}

// ---- CSR build: exclusive scan (single block, 1024 threads x 10 elems) ----
__global__ __launch_bounds__(1024) void k_scan(const int* __restrict__ deg,
                                               int* __restrict__ rowptr) {
  __shared__ int part[1024];
  int t = threadIdx.x;
  int base = t * 10;
  int local[10];
  int s = 0;
  #pragma unroll
  for (int j = 0; j < 10; j++) {
    int i = base + j;
    local[j] = (i < NN) ? deg[i] : 0;
    s += local[j];
  }
  part[t] = s;
  __syncthreads();
  for (int off = 1; off < 1024; off <<= 1) {
    int v = (t >= off) ? part[t - off] : 0;
    __syncthreads();
    part[t] += v;
    __syncthreads();
  }
  int prefix = (t > 0) ? part[t - 1] : 0;
  #pragma unroll
  for (int j = 0; j < 10; j++) {
    int i = base + j;
    if (i < NN) rowptr[i] = prefix;
    prefix += local[j];
  }
  if (t == 1023) rowptr[NN] = prefix;
}

// ---- CSR build: fill ----
__global__ void k_fill(const int* __restrict__ ei, const int* __restrict__ rowptr,
                       int* __restrict__ cursor, int* __restrict__ csr_eid,
                       int* __restrict__ csr_src, int* __restrict__ csr_dst) {
  int e = blockIdx.x * blockDim.x + threadIdx.x;
  if (e >= NE) return;
  int d = ei[NE + e];
  int slot = atomicAdd(&cursor[d], 1);
  int pos = rowptr[d] + slot;
  csr_eid[pos] = e;
  csr_src[pos] = ei[e];
  csr_dst[pos] = d;
}

// ---- ea_csr permute + loop_attr mean, fused (one gather pass) ----
__global__ __launch_bounds__(256) void k_eal(const int* __restrict__ csr_eid,
                                             const float* __restrict__ eattr,
                                             const int* __restrict__ rowptr,
                                             float* __restrict__ ea_csr,
                                             float* __restrict__ loop_attr) {
  int wave = threadIdx.x >> 6, lane = threadIdx.x & 63;
  int d = blockIdx.x * 4 + wave;
  if (d >= NN) return;
  int g = lane >> 4, k = lane & 15;
  int b = rowptr[d], n = rowptr[d + 1] - b;
  float s = 0.f;
  for (int i = g; i < n; i += 4) {
    float v = eattr[(size_t)csr_eid[b + i] * ED + k];
    ea_csr[(size_t)(b + i) * ED + k] = v;
    s += v;
  }
  s += __shfl_xor(s, 16, 64);
  s += __shfl_xor(s, 32, 64);
  if (g == 0) loop_attr[d * ED + k] = s / fmaxf((float)n, 1.0f);
}

// ---- Wpk for ALL 3 layers in one dispatch ----
// Wpk[l][((h*32 + cp)*16 + k)*2 + j] = We_l[k][h*64 + 2*cp + j]
__global__ void k_wet3(const float* __restrict__ We0, const float* __restrict__ We1,
                       const float* __restrict__ We2, float* __restrict__ Wpk) {
  int i = blockIdx.x * blockDim.x + threadIdx.x;
  if (i >= 3 * ED * HC) return;
  int l = i / (ED * HC);
  int r = i - l * (ED * HC);
  const float* We = (l == 0) ? We0 : (l == 1) ? We1 : We2;
  int j  = r & 1;
  int k  = (r >> 1) & 15;
  int cp = (r >> 5) & 31;
  int h  = r >> 10;
  Wpk[i] = We[k * HC + h * CD + cp * 2 + j];
}

// ---- xl = h @ Wl + bl  (node-major xl[node][hc], contiguous 1280B rows) ----
template <int D>
__global__ __launch_bounds__(320) void k_xl(const float* __restrict__ h,
                                            const float* __restrict__ Wl,
                                            const float* __restrict__ bl,
                                            float* __restrict__ xl) {
  constexpr int NPB = 8;
  int node0 = blockIdx.x * NPB;
  int t = threadIdx.x;  // output column 0..319
  float acc[NPB];
  #pragma unroll
  for (int i = 0; i < NPB; i++) acc[i] = 0.f;
  for (int k = 0; k < D; k += 4) {
    float w0 = Wl[(k + 0) * HC + t];
    float w1 = Wl[(k + 1) * HC + t];
    float w2 = Wl[(k + 2) * HC + t];
    float w3 = Wl[(k + 3) * HC + t];
    #pragma unroll
    for (int i = 0; i < NPB; i++) {
      float4 hv = *(const float4*)(h + (size_t)(node0 + i) * D + k);
      acc[i] += hv.x * w0 + hv.y * w1 + hv.z * w2 + hv.w * w3;
    }
  }
  float bv = bl[t];
  #pragma unroll
  for (int i = 0; i < NPB; i++)
    xl[(size_t)(node0 + i) * HC + t] = acc[i] + bv;
}

// ---- scores: ONE THREAD PER (EDGE, HEAD); writes w = exp(clamped score).
// R14 packed body; node-major xl addressing; head-clustered XCD mapping
// (per-XCD line working set = one head's 2.56MB of lines -> L2-resident).
__global__ __launch_bounds__(256) void k_score(
    const int* __restrict__ csr_src, const int* __restrict__ csr_dst,
    const float* __restrict__ ea_csr, const float* __restrict__ loop_attr,
    const float* __restrict__ xl, const float* __restrict__ Wpk,
    const float* __restrict__ att, float* __restrict__ wP) {
  int bid = blockIdx.x;                       // 0..TOTB-1
  int w = (bid & 7) * PERX + (bid >> 3);      // work item, contiguous per XCD
  int h = w / PB;                             // head (uniform, magic-div)
  int lb = w - h * PB;                        // p-slice within head
  int p = lb * 256 + threadIdx.x;
  if (p >= EF) return;
  int s, d;
  const float* ea;
  if (p < NE) { s = csr_src[p]; d = csr_dst[p]; ea = ea_csr + (size_t)p * ED; }
  else        { s = d = p - NE; ea = loop_attr + (size_t)(p - NE) * ED; }
  float eas[16];
  {
    const float4* q = (const float4*)ea;
    float4 t0 = q[0], t1 = q[1], t2 = q[2], t3 = q[3];
    eas[0] = t0.x;  eas[1] = t0.y;  eas[2] = t0.z;  eas[3] = t0.w;
    eas[4] = t1.x;  eas[5] = t1.y;  eas[6] = t1.z;  eas[7] = t1.w;
    eas[8] = t2.x;  eas[9] = t2.y;  eas[10] = t2.z; eas[11] = t2.w;
    eas[12] = t3.x; eas[13] = t3.y; eas[14] = t3.z; eas[15] = t3.w;
  }
  const float* xsrow = xl + (size_t)s * HC + h * CD;   // node-major
  const float* xdrow = xl + (size_t)d * HC + h * CD;
  const f2* wp = (const f2*)Wpk + (size_t)h * (CD / 2) * ED;  // [32 pairs][16 k]
  const f2* ap = (const f2*)(att + (size_t)h * CD);           // pairs contiguous
  f2 sc2 = {0.f, 0.f};
  const f2 zero = {0.f, 0.f};
  #pragma unroll 4
  for (int cb = 0; cb < CD; cb += 4) {  // 2 channel-pairs per iter, 16 iters
    int cp = cb >> 1;
    float4 xs4 = *(const float4*)(xsrow + cb);
    float4 xd4 = *(const float4*)(xdrow + cb);
    const f2* w0 = wp + (size_t)cp * ED;
    const f2* w1 = w0 + ED;
    f2 z0 = f2{xs4.x, xs4.y} + f2{xd4.x, xd4.y};   // v_pk_add_f32
    f2 z1 = f2{xs4.z, xs4.w} + f2{xd4.z, xd4.w};
    #pragma unroll
    for (int k = 0; k < ED; k++) {                 // 2x v_pk_fma_f32 per k
      z0 += w0[k] * eas[k];
      z1 += w1[k] * eas[k];
    }
    // leaky: max(z,0) + NEG*min(z,0)  (packed, branchless, exact)
    z0 = __builtin_elementwise_max(z0, zero) + NEG * __builtin_elementwise_min(z0, zero);
    z1 = __builtin_elementwise_max(z1, zero) + NEG * __builtin_elementwise_min(z1, zero);
    sc2 += z0 * ap[cp];
    sc2 += z1 * ap[cp + 1];
  }
  float sc = sc2.x + sc2.y;
  sc = fminf(fmaxf(sc, -60.f), 60.f);  // clamp never binds for sane inputs
  wP[(size_t)h * EFP + p] = __expf(sc);
}

// ---- aggregation A (fallback, R23): block per node, wave per head ----
__global__ __launch_bounds__(320) void k_agg(
    const int* __restrict__ csr_src, const int* __restrict__ rowptr,
    const float* __restrict__ wP, const float* __restrict__ xl,
    const float* __restrict__ bias, float* __restrict__ out) {
  __shared__ float s_v[NH][CD];
  int h = threadIdx.x >> 6, lane = threadIdx.x & 63;
  int d = blockIdx.x;
  int b = rowptr[d], pe = rowptr[d + 1];
  const float* sp = wP + (size_t)h * EFP;
  const float* xlh = xl + h * CD + lane;               // node-major layout
  float dn = sp[NE + d];
  float acc = dn * xlh[(size_t)d * HC];
  int p = b;
  for (; p + 8 <= pe; p += 8) {
    int s0 = csr_src[p + 0], s1 = csr_src[p + 1];
    int s2 = csr_src[p + 2], s3 = csr_src[p + 3];
    int s4 = csr_src[p + 4], s5 = csr_src[p + 5];
    int s6 = csr_src[p + 6], s7 = csr_src[p + 7];
    float w0 = sp[p + 0], w1 = sp[p + 1], w2 = sp[p + 2], w3 = sp[p + 3];
    float w4 = sp[p + 4], w5 = sp[p + 5], w6 = sp[p + 6], w7 = sp[p + 7];
    float x0 = xlh[(size_t)s0 * HC];
    float x1 = xlh[(size_t)s1 * HC];
    float x2 = xlh[(size_t)s2 * HC];
    float x3 = xlh[(size_t)s3 * HC];
    float x4 = xlh[(size_t)s4 * HC];
    float x5 = xlh[(size_t)s5 * HC];
    float x6 = xlh[(size_t)s6 * HC];
    float x7 = xlh[(size_t)s7 * HC];
    dn += ((w0 + w1) + (w2 + w3)) + ((w4 + w5) + (w6 + w7));
    acc += ((w0 * x0 + w1 * x1) + (w2 * x2 + w3 * x3)) +
           ((w4 * x4 + w5 * x5) + (w6 * x6 + w7 * x7));
  }
  for (; p + 4 <= pe; p += 4) {
    int s0 = csr_src[p + 0], s1 = csr_src[p + 1];
    int s2 = csr_src[p + 2], s3 = csr_src[p + 3];
    float w0 = sp[p + 0], w1 = sp[p + 1], w2 = sp[p + 2], w3 = sp[p + 3];
    float x0 = xlh[(size_t)s0 * HC];
    float x1 = xlh[(size_t)s1 * HC];
    float x2 = xlh[(size_t)s2 * HC];
    float x3 = xlh[(size_t)s3 * HC];
    dn += (w0 + w1) + (w2 + w3);
    acc += (w0 * x0 + w1 * x1) + (w2 * x2 + w3 * x3);
  }
  for (; p < pe; p++) {
    int s0 = csr_src[p];
    float w0 = sp[p];
    dn += w0;
    acc += w0 * xlh[(size_t)s0 * HC];
  }
  s_v[h][lane] = acc / dn;
  __syncthreads();
  if (h == 0) {
    float v = s_v[0][lane] + s_v[1][lane] + s_v[2][lane] + s_v[3][lane] + s_v[4][lane];
    v = v * (1.0f / NH) + bias[lane];
    v = v > 0.f ? v : expm1f(v);
    out[(size_t)d * CD + lane] = v;
  }
}

// ---- aggregation B: ONE WAVE PER (HEAD,NODE), head-clustered, NON-ATOMIC --
__global__ __launch_bounds__(256) void k_agg2p(
    const int* __restrict__ csr_src, const int* __restrict__ rowptr,
    const float* __restrict__ wP, const float* __restrict__ xl,
    float* __restrict__ partial) {
  int bid = blockIdx.x;
  int b2 = (bid & 7) * PERXA + (bid >> 3);   // contiguous per XCD
  int wv = threadIdx.x >> 6, lane = threadIdx.x & 63;
  int g = b2 * 4 + wv;                        // head-major wave id
  if (g >= NW_AGG) return;
  int h = g / NN;                             // uniform (magic-div)
  int d = g - h * NN;
  int b = rowptr[d], pe = rowptr[d + 1];
  const float* sp = wP + (size_t)h * EFP;
  const float* xlh = xl + h * CD + lane;      // node-major, head slice
  float dn = sp[NE + d];
  float acc = dn * xlh[(size_t)d * HC];
  int p = b;
  for (; p + 8 <= pe; p += 8) {
    int s0 = csr_src[p + 0], s1 = csr_src[p + 1];
    int s2 = csr_src[p + 2], s3 = csr_src[p + 3];
    int s4 = csr_src[p + 4], s5 = csr_src[p + 5];
    int s6 = csr_src[p + 6], s7 = csr_src[p + 7];
    float w0 = sp[p + 0], w1 = sp[p + 1], w2 = sp[p + 2], w3 = sp[p + 3];
    float w4 = sp[p + 4], w5 = sp[p + 5], w6 = sp[p + 6], w7 = sp[p + 7];
    float x0 = xlh[(size_t)s0 * HC];
    float x1 = xlh[(size_t)s1 * HC];
    float x2 = xlh[(size_t)s2 * HC];
    float x3 = xlh[(size_t)s3 * HC];
    float x4 = xlh[(size_t)s4 * HC];
    float x5 = xlh[(size_t)s5 * HC];
    float x6 = xlh[(size_t)s6 * HC];
    float x7 = xlh[(size_t)s7 * HC];
    dn += ((w0 + w1) + (w2 + w3)) + ((w4 + w5) + (w6 + w7));
    acc += ((w0 * x0 + w1 * x1) + (w2 * x2 + w3 * x3)) +
           ((w4 * x4 + w5 * x5) + (w6 * x6 + w7 * x7));
  }
  for (; p + 4 <= pe; p += 4) {
    int s0 = csr_src[p + 0], s1 = csr_src[p + 1];
    int s2 = csr_src[p + 2], s3 = csr_src[p + 3];
    float w0 = sp[p + 0], w1 = sp[p + 1], w2 = sp[p + 2], w3 = sp[p + 3];
    float x0 = xlh[(size_t)s0 * HC];
    float x1 = xlh[(size_t)s1 * HC];
    float x2 = xlh[(size_t)s2 * HC];
    float x3 = xlh[(size_t)s3 * HC];
    dn += (w0 + w1) + (w2 + w3);
    acc += (w0 * x0 + w1 * x1) + (w2 * x2 + w3 * x3);
  }
  for (; p < pe; p++) {
    int s0 = csr_src[p];
    float w0 = sp[p];
    dn += w0;
    acc += w0 * xlh[(size_t)s0 * HC];
  }
  partial[(size_t)g * CD + lane] = acc / dn;  // coalesced 256B per wave
}

// ---- combine from partials: out = elu(mean_h partial + bias) ----
__global__ __launch_bounds__(256) void k_combp(const float* __restrict__ partial,
                                               const float* __restrict__ bias,
                                               float* __restrict__ out) {
  int idx = blockIdx.x * blockDim.x + threadIdx.x;  // d*CD + c
  if (idx >= NN * CD) return;
  int c = idx & (CD - 1);
  float v = partial[idx];
  #pragma unroll
  for (int h = 1; h < NH; h++)
    v += partial[(size_t)h * NN * CD + idx];
  v = v * (1.0f / NH) + bias[c];
  v = v > 0.f ? v : expm1f(v);
  out[idx] = v;
}

static inline size_t aln(size_t x) { return (x + 255) & ~(size_t)255; }

extern "C" void kernel_launch(void* const* d_in, const int* in_sizes, int n_in,
                              void* d_out, int out_size, void* d_ws, size_t ws_size,
                              hipStream_t stream) {
  const float* x = (const float*)d_in[0];
  const int* ei = (const int*)d_in[1];      // [2, NE]: src row then dst row
  const float* eattr = (const float*)d_in[2];

  char* w = (char*)d_ws;
  int* degi      = (int*)w;                 w += aln(NN * 4);
  int* cursor    = (int*)w;                 w += aln(NN * 4);
  int* rowptr    = (int*)w;                 w += aln((NN + 1) * 4);
  int* csr_eid   = (int*)w;                 w += aln((size_t)NE * 4);
  int* csr_src   = (int*)w;                 w += aln((size_t)NE * 4);
  int* csr_dst   = (int*)w;                 w += aln((size_t)NE * 4);
  float* loop_attr = (float*)w;             w += aln((size_t)NN * ED * 4);
  float* ea_csr  = (float*)w;               w += aln((size_t)NE * ED * 4);
  float* xl      = (float*)w;               w += aln((size_t)NN * HC * 4);
  float* wPbuf   = (float*)w;               w += aln((size_t)NH * EFP * 4);
  float* Wpk     = (float*)w;               w += aln((size_t)3 * ED * HC * 4);
  float* hbuf    = (float*)w;               w += aln((size_t)NN * CD * 4);
  float* partial = (float*)w;               w += aln((size_t)NH * NN * CD * 4);
  size_t needed = (size_t)(w - (char*)d_ws);
  bool big_ws = (ws_size >= needed);        // runtime probe; safe either way

  // graph structure + permuted edge attrs + all-layer Wpk (layer-invariant)
  hipMemsetAsync(degi, 0, 2 * aln(NN * 4), stream);   // degi + cursor (adjacent)
  k_count<<<(NE + 255) / 256, 256, 0, stream>>>(ei + NE, degi);
  k_scan<<<1, 1024, 0, stream>>>(degi, rowptr);
  k_fill<<<(NE + 255) / 256, 256, 0, stream>>>(ei, rowptr, cursor, csr_eid, csr_src, csr_dst);
  k_eal<<<(NN + 3) / 4, 256, 0, stream>>>(csr_eid, eattr, rowptr, ea_csr, loop_attr);
  k_wet3<<<(3 * ED * HC + 255) / 256, 256, 0, stream>>>(
      (const float*)d_in[5], (const float*)d_in[10], (const float*)d_in[15], Wpk);

  for (int l = 0; l < 3; l++) {
    const float* Wl  = (const float*)d_in[3 + 5 * l];
    const float* bl  = (const float*)d_in[4 + 5 * l];
    const float* att = (const float*)d_in[6 + 5 * l];
    const float* b   = (const float*)d_in[7 + 5 * l];

    if (l == 0) k_xl<ND><<<NN / 8, 320, 0, stream>>>(x, Wl, bl, xl);
    else        k_xl<CD><<<NN / 8, 320, 0, stream>>>(hbuf, Wl, bl, xl);

    k_score<<<TOTB, 256, 0, stream>>>(csr_src, csr_dst, ea_csr, loop_attr,
                                      xl, Wpk + (size_t)l * ED * HC, att, wPbuf);

    float* dst_out = (l < 2) ? hbuf : (float*)d_out;
    if (big_ws) {
      k_agg2p<<<BL_AGG, 256, 0, stream>>>(csr_src, rowptr, wPbuf, xl, partial);
      k_combp<<<(NN * CD + 255) / 256, 256, 0, stream>>>(partial, b, dst_out);
    } else {
      k_agg<<<NN, 320, 0, stream>>>(csr_src, rowptr, wPbuf, xl, b, dst_out);
    }
  }
}